// Round 13
// baseline (27.576 us; speedup 1.0000x reference)
//
#include <hip/hip_runtime.h>

// Dilated attention, collapsed form.
// q,k,v: [B=4, D=256, N=8192] f32 (n contiguous). out: [B, N, D] f32.
// HEAD_DIM=32, heads H=8, taps {-2,0,+2} along n, 6 zero-pad softmax slots.
//
// R13 == R12 + shuffle-derived halos. Lane = cg*8 + subq, so the halo
// elements k[n0-2],k[n0-1] are lane-1's kc.z,kc.w and k[n0+4],k[n0+5] are
// lane+1's kc.x,kc.y: interior halos come from __shfl_up/down(width=8)
// instead of 16 thin float2 loads per thread. Only edge lanes (subq 0/7)
// load their halo f2 (predicated, issued up-front with all other loads).
// Per-thread bytes through L1/L2 drop 320->~260 B (compulsory minimum);
// thin-request count drops 8x. DS pipe absorbs the 32 extra shuffles.
// History: R1 43; R2 spill 105; R3 59; R4 41/34b; R5 41; R7 39.7/29.3b;
// R8 LDS 36.3b; R9 29.6b; R10 26.3b (swizzle+upfront); R11 27.2b (ILP
// neutral); R12 25.7b (plain stores; ~5 TB/s effective vs L3-resident).

constexpr int Bn = 4;
constexpr int Dd = 256;
constexpr int Nn = 8192;
constexpr int HD = 32;
constexpr int Hh = Dd / HD;          // 8
constexpr float SCALE = 0.17677669529663687f;  // 32^-0.5

typedef float vfloat4 __attribute__((ext_vector_type(4)));

__global__ __launch_bounds__(256) void dilate_attn_kernel(
    const float* __restrict__ q,
    const float* __restrict__ k,
    const float* __restrict__ v,
    float* __restrict__ out)
{
    const int tid  = threadIdx.x;
    const int lane = tid & 63;
    const int subq = lane & 7;            // n-quad within wave (0..7)
    const int cg   = lane >> 3;           // channel group of 4 (0..7)
    const int w    = tid >> 6;            // wave in block (0..3)

    // XCD-chunk swizzle: dispatch i lands on XCD i%8; give XCD x the
    // contiguous orig-chunk [x*256, (x+1)*256).
    const int orig = ((blockIdx.x & 7) << 8) + (blockIdx.x >> 3);   // 2048 blocks
    const int bh   = orig >> 6;           // 64 blocks per (b,h)
    const int h    = bh & (Hh - 1);
    const int b    = bh >> 3;
    // block covers 128 n: 4 waves x 8 quads x 4 n
    const int n0 = ((orig & 63) << 7) + (w << 5) + (subq << 2);

    const int cb = (b * Dd + h * HD + cg * 4) * Nn + n0;   // fits in int
    const float* qb = q + cb;
    const float* kb = k + cb;
    const float* vb = v + cb;

    const bool hasL = (n0 >= 4);          // edge-lane halo validity
    const bool hasR = (n0 + 4 < Nn);
    const bool edgeL = (subq == 0);
    const bool edgeR = (subq == 7);

    // ---- issue ALL loads up-front: q, k-center, v-center, edge halos ----
    float4 qv[4], kc4[4], vc4[4];
    #pragma unroll
    for (int c = 0; c < 4; ++c) {
        const int o = c * Nn;             // uniform -> SGPR base step
        qv[c]  = *reinterpret_cast<const float4*>(qb + o);
        kc4[c] = *reinterpret_cast<const float4*>(kb + o);
        vc4[c] = *reinterpret_cast<const float4*>(vb + o);
    }
    // edge-lane halo loads (predicated; 8 of 64 lanes active per instr)
    float2 kmL[4], vmL[4], kpL[4], vpL[4];
    #pragma unroll
    for (int c = 0; c < 4; ++c) {
        kmL[c] = make_float2(0.f, 0.f);  vmL[c] = make_float2(0.f, 0.f);
        kpL[c] = make_float2(0.f, 0.f);  vpL[c] = make_float2(0.f, 0.f);
    }
    if (edgeL & hasL) {
        #pragma unroll
        for (int c = 0; c < 4; ++c) {
            const int o = c * Nn;
            kmL[c] = *reinterpret_cast<const float2*>(kb + o - 2);
            vmL[c] = *reinterpret_cast<const float2*>(vb + o - 2);
        }
    }
    if (edgeR & hasR) {
        #pragma unroll
        for (int c = 0; c < 4; ++c) {
            const int o = c * Nn;
            kpL[c] = *reinterpret_cast<const float2*>(kb + o + 4);
            vpL[c] = *reinterpret_cast<const float2*>(vb + o + 4);
        }
    }

    // ---- derive halos: interior lanes by shuffle, edge lanes from loads ----
    // km = {k[n0-2],k[n0-1]} = lane-1's kc.z,kc.w ; kp = lane+1's kc.x,kc.y
    float2 km2[4], kp2[4], vm2[4], vp2[4];
    #pragma unroll
    for (int c = 0; c < 4; ++c) {
        float2 km = make_float2(__shfl_up(kc4[c].z, 1, 8),
                                __shfl_up(kc4[c].w, 1, 8));
        float2 kp = make_float2(__shfl_down(kc4[c].x, 1, 8),
                                __shfl_down(kc4[c].y, 1, 8));
        float2 vm = make_float2(__shfl_up(vc4[c].z, 1, 8),
                                __shfl_up(vc4[c].w, 1, 8));
        float2 vp = make_float2(__shfl_down(vc4[c].x, 1, 8),
                                __shfl_down(vc4[c].y, 1, 8));
        km2[c] = edgeL ? kmL[c] : km;
        vm2[c] = edgeL ? vmL[c] : vm;
        kp2[c] = edgeR ? kpL[c] : kp;
        vp2[c] = edgeR ? vpL[c] : vp;
    }

    // ---- phase 1: partial logits for rows n0..n0+3 over 4 channels ----
    // taps per row j (k[n0+j-2], k[n0+j], k[n0+j+2]):
    //  j=0: km.x kc.x kc.z | j=1: km.y kc.y kc.w
    //  j=2: kc.x kc.z kp.x | j=3: kc.y kc.w kp.y
    float s0[4] = {0.f, 0.f, 0.f, 0.f};
    float s1[4] = {0.f, 0.f, 0.f, 0.f};
    float s2[4] = {0.f, 0.f, 0.f, 0.f};
    #pragma unroll
    for (int c = 0; c < 4; ++c) {
        const float4 qc = qv[c];
        const float4 kc = kc4[c];
        const float2 km = km2[c];
        const float2 kp = kp2[c];
        s0[0] = fmaf(qc.x, km.x, s0[0]);
        s1[0] = fmaf(qc.x, kc.x, s1[0]);
        s2[0] = fmaf(qc.x, kc.z, s2[0]);
        s0[1] = fmaf(qc.y, km.y, s0[1]);
        s1[1] = fmaf(qc.y, kc.y, s1[1]);
        s2[1] = fmaf(qc.y, kc.w, s2[1]);
        s0[2] = fmaf(qc.z, kc.x, s0[2]);
        s1[2] = fmaf(qc.z, kc.z, s1[2]);
        s2[2] = fmaf(qc.z, kp.x, s2[2]);
        s0[3] = fmaf(qc.w, kc.y, s0[3]);
        s1[3] = fmaf(qc.w, kc.w, s1[3]);
        s2[3] = fmaf(qc.w, kp.y, s2[3]);
    }

    // reduce across the 8 channel-groups (lane bits 3,4,5); softmax per row
    float p0[4], p1[4], p2[4];
    #pragma unroll
    for (int j = 0; j < 4; ++j) {
        float a = s0[j], bb = s1[j], cc = s2[j];
        a  += __shfl_xor(a,  8, 64); a  += __shfl_xor(a, 16, 64); a  += __shfl_xor(a, 32, 64);
        bb += __shfl_xor(bb, 8, 64); bb += __shfl_xor(bb, 16, 64); bb += __shfl_xor(bb, 32, 64);
        cc += __shfl_xor(cc, 8, 64); cc += __shfl_xor(cc, 16, 64); cc += __shfl_xor(cc, 32, 64);
        a *= SCALE; bb *= SCALE; cc *= SCALE;
        const float m  = fmaxf(fmaxf(a, bb), fmaxf(cc, 0.f));
        const float e0 = __expf(a - m);
        const float e1 = __expf(bb - m);
        const float e2 = __expf(cc - m);
        const float inv = 1.f / (e0 + e1 + e2 + 6.f * __expf(-m));
        p0[j] = e0 * inv; p1[j] = e1 * inv; p2[j] = e2 * inv;
    }

    // ---- phase 3: PV over 4 channels, one 16 B store per row ----
    float t[4][4];                        // [row j][channel c]
    #pragma unroll
    for (int c = 0; c < 4; ++c) {
        const float4 vc = vc4[c];
        const float2 vm = vm2[c];
        const float2 vp = vp2[c];
        t[0][c] = fmaf(p0[0], vm.x, fmaf(p1[0], vc.x, p2[0] * vc.z));
        t[1][c] = fmaf(p0[1], vm.y, fmaf(p1[1], vc.y, p2[1] * vc.w));
        t[2][c] = fmaf(p0[2], vc.x, fmaf(p1[2], vc.z, p2[2] * vp.x));
        t[3][c] = fmaf(p0[3], vc.y, fmaf(p1[3], vc.w, p2[3] * vp.y));
    }

    // out[b][n0+j][h*32 + cg*4 .. +3]: 16 B per lane per row; the wave's
    // 8 channel-groups tile complete 128 B row chunks. Plain cached stores.
    float* ob = out + (b * Nn + n0) * Dd + h * HD + cg * 4;
    #pragma unroll
    for (int j = 0; j < 4; ++j) {
        vfloat4 a = {t[j][0], t[j][1], t[j][2], t[j][3]};
        *reinterpret_cast<vfloat4*>(ob + j * Dd) = a;
    }
}

extern "C" void kernel_launch(void* const* d_in, const int* in_sizes, int n_in,
                              void* d_out, int out_size, void* d_ws, size_t ws_size,
                              hipStream_t stream)
{
    const float* q = (const float*)d_in[0];
    const float* k = (const float*)d_in[1];
    const float* v = (const float*)d_in[2];
    float* out = (float*)d_out;

    // B*H*(N/4) quads x 8 channel-groups = 524288 threads = 2048 blocks
    const int total_threads = Bn * Hh * (Nn / 4) * 8;
    dilate_attn_kernel<<<total_threads / 256, 256, 0, stream>>>(q, k, v, out);
}